// Round 1
// baseline (927.319 us; speedup 1.0000x reference)
//
#include <hip/hip_runtime.h>
#include <math.h>

// ---------------- wave helpers ----------------
__device__ __forceinline__ float wred_sum(float v) {
#pragma unroll
  for (int o = 32; o; o >>= 1) v += __shfl_xor(v, o, 64);
  return v;
}
__device__ __forceinline__ float wred_max(float v) {
#pragma unroll
  for (int o = 32; o; o >>= 1) v = fmaxf(v, __shfl_xor(v, o, 64));
  return v;
}

// ---------------- CSR build ----------------
__global__ void zero_int(int* __restrict__ p, int n) {
  int i = blockIdx.x * blockDim.x + threadIdx.x;
  if (i < n) p[i] = 0;
}

// edges e in [0, E0) come from edge_index; e in [E0, E0+N) are self-loops (node e-E0)
__global__ void hist_kernel(const int* __restrict__ ei, int* __restrict__ cnt, int E0, int N) {
  int e = blockIdx.x * blockDim.x + threadIdx.x;
  if (e >= E0 + N) return;
  int d = (e < E0) ? ei[E0 + e] : (e - E0);
  atomicAdd(&cnt[d], 1);
}

__global__ void scan1(const int* __restrict__ cnt, int* __restrict__ part, int N) {
  __shared__ int lds[256];
  int idx = blockIdx.x * 256 + threadIdx.x;
  int v = (idx < N) ? cnt[idx] : 0;
  lds[threadIdx.x] = v;
  __syncthreads();
  for (int o = 128; o; o >>= 1) {
    if (threadIdx.x < o) lds[threadIdx.x] += lds[threadIdx.x + o];
    __syncthreads();
  }
  if (threadIdx.x == 0) part[blockIdx.x] = lds[0];
}

__global__ void scan2(int* __restrict__ part, int nb, int* __restrict__ rp, int N, int E) {
  __shared__ int lds[256];
  int t = threadIdx.x;
  int v = (t < nb) ? part[t] : 0;
  lds[t] = v;
  __syncthreads();
  for (int o = 1; o < 256; o <<= 1) {
    int x = (t >= o) ? lds[t - o] : 0;
    __syncthreads();
    lds[t] += x;
    __syncthreads();
  }
  part[t] = lds[t] - v;  // exclusive
  if (t == 0) rp[N] = E;
}

__global__ void scan3(const int* __restrict__ cnt, const int* __restrict__ part,
                      int* __restrict__ rp, int N) {
  __shared__ int lds[256];
  int t = threadIdx.x;
  int idx = blockIdx.x * 256 + t;
  int v = (idx < N) ? cnt[idx] : 0;
  lds[t] = v;
  __syncthreads();
  for (int o = 1; o < 256; o <<= 1) {
    int x = (t >= o) ? lds[t - o] : 0;
    __syncthreads();
    lds[t] += x;
    __syncthreads();
  }
  if (idx < N) rp[idx] = part[blockIdx.x] + lds[t] - v;
}

__global__ void fill_kernel(const int* __restrict__ ei, const int* __restrict__ rp,
                            int* __restrict__ cnt, int* __restrict__ col, int E0, int N) {
  int e = blockIdx.x * blockDim.x + threadIdx.x;
  if (e >= E0 + N) return;
  int d, s;
  if (e < E0) { s = ei[e]; d = ei[E0 + e]; }
  else        { s = e - E0; d = s; }
  int pos = rp[d] + atomicAdd(&cnt[d], 1);
  col[pos] = s;
}

// ---------------- emb_w transpose: (C=64, F=128) -> (F,64) ----------------
__global__ void transpose_w(const float* __restrict__ w, float* __restrict__ wt, int F, int C) {
  int i = blockIdx.x * blockDim.x + threadIdx.x;
  if (i < F * C) {
    int f = i / C, c = i % C;
    wt[i] = w[c * F + f];
  }
}

// ---------------- fused GEMM + attention scores ----------------
// xh[n][h][c] = sum_f in[n][f] * w[h][f][c]  (+bias[c]); optionally
// si[n][h] = sum_c xh*a[h][c], sj[n][h] = sum_c xh*a[h][64+c]
// C = 64 always. Wave layout: lane = c, wave -> (h, row-group of 4 rows).
template <int F, int H>
__global__ __launch_bounds__(256) void gemm_kernel(
    const float* __restrict__ in, const float* __restrict__ w,
    const float* __restrict__ bias, const float* __restrict__ a,
    float* __restrict__ xh, float* __restrict__ si, float* __restrict__ sj, int nrows) {
  constexpr int HC = H * 64;
  constexpr int RG = 4 / H;        // row-groups per block (4 waves)
  constexpr int ROWS = RG * 4;     // rows per block
  __shared__ float wlds[H * F * 64];
  int tid = threadIdx.x;
  for (int i = tid; i < H * F * 64; i += 256) wlds[i] = w[i];
  __syncthreads();

  int lane = tid & 63, wv = tid >> 6;
  int h = wv % H, rg = wv / H;
  int n0 = blockIdx.x * ROWS + rg * 4;
  if (n0 >= nrows) return;

  float ai = a ? a[h * 128 + lane] : 0.f;
  float aj = a ? a[h * 128 + 64 + lane] : 0.f;
  float b = bias ? bias[lane] : 0.f;
  float acc[4] = {b, b, b, b};

  const float* xr[4];
#pragma unroll
  for (int r = 0; r < 4; ++r) {
    int n = n0 + r;
    if (n > nrows - 1) n = nrows - 1;  // clamp (grid divides exactly; safety)
    xr[r] = in + (size_t)n * F;
  }

  const float* wbase = wlds + h * F * 64 + lane;
  for (int f = 0; f < F; f += 4) {
    float w0 = wbase[(f + 0) * 64];
    float w1 = wbase[(f + 1) * 64];
    float w2 = wbase[(f + 2) * 64];
    float w3 = wbase[(f + 3) * 64];
#pragma unroll
    for (int r = 0; r < 4; ++r) {
      float4 xv = *reinterpret_cast<const float4*>(xr[r] + f);
      acc[r] = fmaf(xv.x, w0, acc[r]);
      acc[r] = fmaf(xv.y, w1, acc[r]);
      acc[r] = fmaf(xv.z, w2, acc[r]);
      acc[r] = fmaf(xv.w, w3, acc[r]);
    }
  }

#pragma unroll
  for (int r = 0; r < 4; ++r) {
    int n = n0 + r;
    if (n >= nrows) break;
    xh[(size_t)n * HC + h * 64 + lane] = acc[r];
    if (a) {
      float vi = wred_sum(acc[r] * ai);
      float vj = wred_sum(acc[r] * aj);
      if (lane == 0) { si[n * H + h] = vi; sj[n * H + h] = vj; }
    }
  }
}

// ---------------- per-node online-softmax aggregation ----------------
// One wave per node. H==2: lane owns features (2*lane, 2*lane+1) of the 128-wide
// concat row. H==1: lane owns feature lane of 64.
template <int H>
__global__ __launch_bounds__(256) void agg_kernel(
    const float* __restrict__ xh, const float* __restrict__ si_g, const float* __restrict__ sj_g,
    const int* __restrict__ rp, const int* __restrict__ col,
    float* __restrict__ out, int N) {
  int lane = threadIdx.x & 63, wv = threadIdx.x >> 6;
  int n = blockIdx.x * 4 + wv;
  if (n >= N) return;
  int base = rp[n];
  int deg = rp[n + 1] - base;

  float si0 = si_g[n * H];
  float si1 = (H == 2) ? si_g[n * H + 1] : 0.f;
  float m0 = -INFINITY, m1 = -INFINITY;
  float d0 = 0.f, d1 = 0.f;
  float a0 = 0.f, a1 = 0.f;

  for (int start = 0; start < deg; start += 64) {
    int k = start + lane;
    bool vld = k < deg;
    int s = vld ? col[base + k] : 0;
    float al0 = -INFINITY, al1 = -INFINITY;
    if (vld) {
      if (H == 2) {
        float2 sjv = *reinterpret_cast<const float2*>(sj_g + (size_t)s * 2);
        float t0 = si0 + sjv.x; al0 = (t0 > 0.f) ? t0 : 0.2f * t0;
        float t1 = si1 + sjv.y; al1 = (t1 > 0.f) ? t1 : 0.2f * t1;
      } else {
        float t0 = si0 + sj_g[s]; al0 = (t0 > 0.f) ? t0 : 0.2f * t0;
      }
    }
    // chunk max + online rescale
    float nm0 = fmaxf(m0, wred_max(al0));
    float r0 = __expf(m0 - nm0);
    d0 *= r0; a0 *= r0; m0 = nm0;
    float p0 = vld ? __expf(al0 - m0) : 0.f;
    d0 += wred_sum(p0);
    float p1 = 0.f;
    if (H == 2) {
      float nm1 = fmaxf(m1, wred_max(al1));
      float r1 = __expf(m1 - nm1);
      d1 *= r1; a1 *= r1; m1 = nm1;
      p1 = vld ? __expf(al1 - m1) : 0.f;
      d1 += wred_sum(p1);
    }

    int cc = min(64, deg - start);
    if (H == 2) {
      for (int kk = 0; kk < cc; ++kk) {
        int ss = __shfl(s, kk, 64);
        float q0 = __shfl(p0, kk, 64);
        float q1 = __shfl(p1, kk, 64);
        float2 v = *reinterpret_cast<const float2*>(xh + (size_t)ss * 128 + lane * 2);
        float q = (lane < 32) ? q0 : q1;
        a0 = fmaf(q, v.x, a0);
        a1 = fmaf(q, v.y, a1);
      }
    } else {
      for (int kk = 0; kk < cc; ++kk) {
        int ss = __shfl(s, kk, 64);
        float q0 = __shfl(p0, kk, 64);
        a0 = fmaf(q0, xh[(size_t)ss * 64 + lane], a0);
      }
    }
  }

  if (H == 2) {
    float dd = (lane < 32) ? d0 : d1;
    float inv = 1.f / (dd + 1e-16f);
    float v0 = a0 * inv, v1 = a1 * inv;
    v0 = (v0 > 0.f) ? v0 : expm1f(v0);
    v1 = (v1 > 0.f) ? v1 : expm1f(v1);
    float2 o; o.x = v0; o.y = v1;
    *reinterpret_cast<float2*>(out + (size_t)n * 128 + lane * 2) = o;
  } else {
    float inv = 1.f / (d0 + 1e-16f);
    float v0 = a0 * inv;
    v0 = (v0 > 0.f) ? v0 : expm1f(v0);
    out[(size_t)n * 64 + lane] = v0;
  }
}

// ---------------- launch ----------------
extern "C" void kernel_launch(void* const* d_in, const int* in_sizes, int n_in,
                              void* d_out, int out_size, void* d_ws, size_t ws_size,
                              hipStream_t stream) {
  const float* x     = (const float*)d_in[0];
  const int*   ei    = (const int*)d_in[1];
  const float* emb_w = (const float*)d_in[2];
  const float* emb_b = (const float*)d_in[3];
  const float* w0    = (const float*)d_in[4];
  const float* a0    = (const float*)d_in[5];
  const float* w1    = (const float*)d_in[6];
  const float* a1    = (const float*)d_in[7];
  const float* w2    = (const float*)d_in[8];
  const float* a2    = (const float*)d_in[9];

  const int IN_CH = 128;
  int N  = in_sizes[0] / IN_CH;   // 50000
  int E0 = in_sizes[1] / 2;       // 800000
  int E  = E0 + N;                // with self-loops

  // workspace carve (256B aligned)
  char* p = (char*)d_ws;
  auto alloc = [&](size_t bytes) -> char* {
    char* r = p;
    p += (bytes + 255) & ~(size_t)255;
    return r;
  };
  float* hA   = (float*)alloc((size_t)N * 128 * 4);
  float* hB   = (float*)alloc((size_t)N * 128 * 4);
  float* xh   = (float*)alloc((size_t)N * 128 * 4);
  float* si   = (float*)alloc((size_t)N * 2 * 4);
  float* sj   = (float*)alloc((size_t)N * 2 * 4);
  float* embT = (float*)alloc(128 * 64 * 4);
  int* rp   = (int*)alloc((size_t)(N + 1) * 4);
  int* cnt  = (int*)alloc((size_t)N * 4);
  int* col  = (int*)alloc((size_t)E * 4);
  int* part = (int*)alloc(1024);

  dim3 blk(256);
  int gN = (N + 255) / 256;     // 196
  int gE = (E + 255) / 256;

  // CSR build
  zero_int<<<gN, blk, 0, stream>>>(cnt, N);
  hist_kernel<<<gE, blk, 0, stream>>>(ei, cnt, E0, N);
  scan1<<<gN, blk, 0, stream>>>(cnt, part, N);
  scan2<<<1, blk, 0, stream>>>(part, gN, rp, N, E);
  scan3<<<gN, blk, 0, stream>>>(cnt, part, rp, N);
  zero_int<<<gN, blk, 0, stream>>>(cnt, N);
  fill_kernel<<<gE, blk, 0, stream>>>(ei, rp, cnt, col, E0, N);

  // embedding: h = x @ emb_w.T + emb_b   (transpose weights first)
  transpose_w<<<(128 * 64 + 255) / 256, blk, 0, stream>>>(emb_w, embT, 128, 64);
  gemm_kernel<128, 1><<<(N + 15) / 16, blk, 0, stream>>>(x, embT, emb_b, nullptr, hA, nullptr, nullptr, N);

  // layer 0: F=64, H=2
  gemm_kernel<64, 2><<<(N + 7) / 8, blk, 0, stream>>>(hA, w0, nullptr, a0, xh, si, sj, N);
  agg_kernel<2><<<(N + 3) / 4, blk, 0, stream>>>(xh, si, sj, rp, col, hB, N);

  // layer 1: F=128, H=2
  gemm_kernel<128, 2><<<(N + 7) / 8, blk, 0, stream>>>(hB, w1, nullptr, a1, xh, si, sj, N);
  agg_kernel<2><<<(N + 3) / 4, blk, 0, stream>>>(xh, si, sj, rp, col, hA, N);

  // layer 2: F=128, H=1 -> output
  gemm_kernel<128, 1><<<(N + 15) / 16, blk, 0, stream>>>(hA, w2, nullptr, a2, xh, si, sj, N);
  agg_kernel<1><<<(N + 3) / 4, blk, 0, stream>>>(xh, si, sj, rp, col, (float*)d_out, N);
}

// Round 2
// 610.475 us; speedup vs baseline: 1.5190x; 1.5190x over previous
//
#include <hip/hip_runtime.h>
#include <math.h>

// ---------------- wave helpers ----------------
__device__ __forceinline__ float wred_sum(float v) {
#pragma unroll
  for (int o = 32; o; o >>= 1) v += __shfl_xor(v, o, 64);
  return v;
}
__device__ __forceinline__ float wred_max(float v) {
#pragma unroll
  for (int o = 32; o; o >>= 1) v = fmaxf(v, __shfl_xor(v, o, 64));
  return v;
}

// ---------------- CSR build ----------------
__global__ void zero_int(int* __restrict__ p, int n) {
  int i = blockIdx.x * blockDim.x + threadIdx.x;
  if (i < n) p[i] = 0;
}

// edges e in [0, E0) come from edge_index; e in [E0, E0+N) are self-loops (node e-E0)
__global__ void hist_kernel(const int* __restrict__ ei, int* __restrict__ cnt, int E0, int N) {
  int e = blockIdx.x * blockDim.x + threadIdx.x;
  if (e >= E0 + N) return;
  int d = (e < E0) ? ei[E0 + e] : (e - E0);
  atomicAdd(&cnt[d], 1);
}

__global__ void scan1(const int* __restrict__ cnt, int* __restrict__ part, int N) {
  __shared__ int lds[256];
  int idx = blockIdx.x * 256 + threadIdx.x;
  int v = (idx < N) ? cnt[idx] : 0;
  lds[threadIdx.x] = v;
  __syncthreads();
  for (int o = 128; o; o >>= 1) {
    if (threadIdx.x < o) lds[threadIdx.x] += lds[threadIdx.x + o];
    __syncthreads();
  }
  if (threadIdx.x == 0) part[blockIdx.x] = lds[0];
}

__global__ void scan2(int* __restrict__ part, int nb, int* __restrict__ rp, int N, int E) {
  __shared__ int lds[256];
  int t = threadIdx.x;
  int v = (t < nb) ? part[t] : 0;
  lds[t] = v;
  __syncthreads();
  for (int o = 1; o < 256; o <<= 1) {
    int x = (t >= o) ? lds[t - o] : 0;
    __syncthreads();
    lds[t] += x;
    __syncthreads();
  }
  part[t] = lds[t] - v;  // exclusive
  if (t == 0) rp[N] = E;
}

__global__ void scan3(const int* __restrict__ cnt, const int* __restrict__ part,
                      int* __restrict__ rp, int N) {
  __shared__ int lds[256];
  int t = threadIdx.x;
  int idx = blockIdx.x * 256 + t;
  int v = (idx < N) ? cnt[idx] : 0;
  lds[t] = v;
  __syncthreads();
  for (int o = 1; o < 256; o <<= 1) {
    int x = (t >= o) ? lds[t - o] : 0;
    __syncthreads();
    lds[t] += x;
    __syncthreads();
  }
  if (idx < N) rp[idx] = part[blockIdx.x] + lds[t] - v;
}

__global__ void fill_kernel(const int* __restrict__ ei, const int* __restrict__ rp,
                            int* __restrict__ cnt, int* __restrict__ col, int E0, int N) {
  int e = blockIdx.x * blockDim.x + threadIdx.x;
  if (e >= E0 + N) return;
  int d, s;
  if (e < E0) { s = ei[e]; d = ei[E0 + e]; }
  else        { s = e - E0; d = s; }
  int pos = rp[d] + atomicAdd(&cnt[d], 1);
  col[pos] = s;
}

// ---------------- emb_w transpose: (C=64, F=128) -> [f][c] ----------------
__global__ void transpose_w(const float* __restrict__ w, float* __restrict__ wt, int F, int C) {
  int i = blockIdx.x * blockDim.x + threadIdx.x;
  if (i < F * C) {
    int f = i / C, c = i % C;
    wt[i] = w[c * F + f];
  }
}

// ---------------- fused GEMM + attention scores ----------------
// One head per block (blockIdx.y = h). Block = 4 waves x 16 rows = 64 rows.
// Weights [h][f][c] staged to LDS as [f][c] (lane = c -> 2-way aliasing, free).
// xh[n][h*64+c] = sum_f in[n][f]*w[h][f][c] (+bias[c]); optional scores:
// si[n][h] = sum_c xh*a[h][c], sj[n][h] = sum_c xh*a[h][64+c].
template <int F, int H>
__global__ __launch_bounds__(256, 4) void gemm_kernel(
    const float* __restrict__ in, const float* __restrict__ w,
    const float* __restrict__ bias, const float* __restrict__ a,
    float* __restrict__ xh, float* __restrict__ si, float* __restrict__ sj,
    int nrows) {
  __shared__ float wlds[F * 64];
  const int tid = threadIdx.x;
  const int h = blockIdx.y;

  {  // coalesced float4 weight staging: F*64 floats = F*16 float4
    const float4* ws = reinterpret_cast<const float4*>(w + (size_t)h * F * 64);
    float4* wd = reinterpret_cast<float4*>(wlds);
#pragma unroll
    for (int i = 0; i < (F * 16) / 256; ++i) wd[i * 256 + tid] = ws[i * 256 + tid];
  }
  __syncthreads();

  const int lane = tid & 63;
  const int wv = tid >> 6;
  int n0 = blockIdx.x * 64 + wv * 16;
  if (n0 > nrows - 16) n0 = nrows - 16;  // tail waves recompute identical rows (benign)

  const float ai = a ? a[h * 128 + lane] : 0.f;
  const float aj = a ? a[h * 128 + 64 + lane] : 0.f;
  const float b = bias ? bias[lane] : 0.f;

  float acc[16];
#pragma unroll
  for (int r = 0; r < 16; ++r) acc[r] = b;

  const float* xp = in + (size_t)n0 * F;
  const float* wl = wlds + lane;

#pragma unroll 1
  for (int f = 0; f < F; f += 8) {
    float wr[8];
#pragma unroll
    for (int q = 0; q < 8; ++q) wr[q] = wl[(f + q) * 64];
#pragma unroll
    for (int r = 0; r < 16; ++r) {
      const float4 x0 = *reinterpret_cast<const float4*>(xp + r * F + f);
      const float4 x1 = *reinterpret_cast<const float4*>(xp + r * F + f + 4);
      float t = acc[r];
      t = fmaf(x0.x, wr[0], t);
      t = fmaf(x0.y, wr[1], t);
      t = fmaf(x0.z, wr[2], t);
      t = fmaf(x0.w, wr[3], t);
      t = fmaf(x1.x, wr[4], t);
      t = fmaf(x1.y, wr[5], t);
      t = fmaf(x1.z, wr[6], t);
      acc[r] = fmaf(x1.w, wr[7], t);
    }
  }

  constexpr int HC = H * 64;
#pragma unroll
  for (int r = 0; r < 16; ++r) {
    const int n = n0 + r;
    xh[(size_t)n * HC + h * 64 + lane] = acc[r];
  }
  if (a) {
#pragma unroll 1
    for (int r = 0; r < 16; ++r) {
      const int n = n0 + r;
      float vi = wred_sum(acc[r] * ai);
      float vj = wred_sum(acc[r] * aj);
      if (lane == 0) { si[n * H + h] = vi; sj[n * H + h] = vj; }
    }
  }
}

// ---------------- per-node online-softmax aggregation ----------------
// One wave per node. H==2: lane owns features (2*lane, 2*lane+1) of the 128-wide
// concat row. H==1: lane owns feature lane of 64.
template <int H>
__global__ __launch_bounds__(256) void agg_kernel(
    const float* __restrict__ xh, const float* __restrict__ si_g, const float* __restrict__ sj_g,
    const int* __restrict__ rp, const int* __restrict__ col,
    float* __restrict__ out, int N) {
  int lane = threadIdx.x & 63, wv = threadIdx.x >> 6;
  int n = blockIdx.x * 4 + wv;
  if (n >= N) return;
  int base = rp[n];
  int deg = rp[n + 1] - base;

  float si0 = si_g[n * H];
  float si1 = (H == 2) ? si_g[n * H + 1] : 0.f;
  float m0 = -INFINITY, m1 = -INFINITY;
  float d0 = 0.f, d1 = 0.f;
  float a0 = 0.f, a1 = 0.f;

  for (int start = 0; start < deg; start += 64) {
    int k = start + lane;
    bool vld = k < deg;
    int s = vld ? col[base + k] : 0;
    float al0 = -INFINITY, al1 = -INFINITY;
    if (vld) {
      if (H == 2) {
        float2 sjv = *reinterpret_cast<const float2*>(sj_g + (size_t)s * 2);
        float t0 = si0 + sjv.x; al0 = (t0 > 0.f) ? t0 : 0.2f * t0;
        float t1 = si1 + sjv.y; al1 = (t1 > 0.f) ? t1 : 0.2f * t1;
      } else {
        float t0 = si0 + sj_g[s]; al0 = (t0 > 0.f) ? t0 : 0.2f * t0;
      }
    }
    // chunk max + online rescale
    float nm0 = fmaxf(m0, wred_max(al0));
    float r0 = __expf(m0 - nm0);
    d0 *= r0; a0 *= r0; m0 = nm0;
    float p0 = vld ? __expf(al0 - m0) : 0.f;
    d0 += wred_sum(p0);
    float p1 = 0.f;
    if (H == 2) {
      float nm1 = fmaxf(m1, wred_max(al1));
      float r1 = __expf(m1 - nm1);
      d1 *= r1; a1 *= r1; m1 = nm1;
      p1 = vld ? __expf(al1 - m1) : 0.f;
      d1 += wred_sum(p1);
    }

    int cc = min(64, deg - start);
    if (H == 2) {
      for (int kk = 0; kk < cc; ++kk) {
        int ss = __shfl(s, kk, 64);
        float q0 = __shfl(p0, kk, 64);
        float q1 = __shfl(p1, kk, 64);
        float2 v = *reinterpret_cast<const float2*>(xh + (size_t)ss * 128 + lane * 2);
        float q = (lane < 32) ? q0 : q1;
        a0 = fmaf(q, v.x, a0);
        a1 = fmaf(q, v.y, a1);
      }
    } else {
      for (int kk = 0; kk < cc; ++kk) {
        int ss = __shfl(s, kk, 64);
        float q0 = __shfl(p0, kk, 64);
        a0 = fmaf(q0, xh[(size_t)ss * 64 + lane], a0);
      }
    }
  }

  if (H == 2) {
    float dd = (lane < 32) ? d0 : d1;
    float inv = 1.f / (dd + 1e-16f);
    float v0 = a0 * inv, v1 = a1 * inv;
    v0 = (v0 > 0.f) ? v0 : expm1f(v0);
    v1 = (v1 > 0.f) ? v1 : expm1f(v1);
    float2 o; o.x = v0; o.y = v1;
    *reinterpret_cast<float2*>(out + (size_t)n * 128 + lane * 2) = o;
  } else {
    float inv = 1.f / (d0 + 1e-16f);
    float v0 = a0 * inv;
    v0 = (v0 > 0.f) ? v0 : expm1f(v0);
    out[(size_t)n * 64 + lane] = v0;
  }
}

// ---------------- launch ----------------
extern "C" void kernel_launch(void* const* d_in, const int* in_sizes, int n_in,
                              void* d_out, int out_size, void* d_ws, size_t ws_size,
                              hipStream_t stream) {
  const float* x     = (const float*)d_in[0];
  const int*   ei    = (const int*)d_in[1];
  const float* emb_w = (const float*)d_in[2];
  const float* emb_b = (const float*)d_in[3];
  const float* w0    = (const float*)d_in[4];
  const float* a0    = (const float*)d_in[5];
  const float* w1    = (const float*)d_in[6];
  const float* a1    = (const float*)d_in[7];
  const float* w2    = (const float*)d_in[8];
  const float* a2    = (const float*)d_in[9];

  const int IN_CH = 128;
  int N  = in_sizes[0] / IN_CH;   // 50000
  int E0 = in_sizes[1] / 2;       // 800000
  int E  = E0 + N;                // with self-loops

  // workspace carve (256B aligned)
  char* p = (char*)d_ws;
  auto alloc = [&](size_t bytes) -> char* {
    char* r = p;
    p += (bytes + 255) & ~(size_t)255;
    return r;
  };
  float* hA   = (float*)alloc((size_t)N * 128 * 4);
  float* hB   = (float*)alloc((size_t)N * 128 * 4);
  float* xh   = (float*)alloc((size_t)N * 128 * 4);
  float* si   = (float*)alloc((size_t)N * 2 * 4);
  float* sj   = (float*)alloc((size_t)N * 2 * 4);
  float* embT = (float*)alloc(128 * 64 * 4);
  int* rp   = (int*)alloc((size_t)(N + 1) * 4);
  int* cnt  = (int*)alloc((size_t)N * 4);
  int* col  = (int*)alloc((size_t)E * 4);
  int* part = (int*)alloc(1024);

  dim3 blk(256);
  int gN = (N + 255) / 256;     // 196
  int gE = (E + 255) / 256;

  // CSR build
  zero_int<<<gN, blk, 0, stream>>>(cnt, N);
  hist_kernel<<<gE, blk, 0, stream>>>(ei, cnt, E0, N);
  scan1<<<gN, blk, 0, stream>>>(cnt, part, N);
  scan2<<<1, blk, 0, stream>>>(part, gN, rp, N, E);
  scan3<<<gN, blk, 0, stream>>>(cnt, part, rp, N);
  zero_int<<<gN, blk, 0, stream>>>(cnt, N);
  fill_kernel<<<gE, blk, 0, stream>>>(ei, rp, cnt, col, E0, N);

  // embedding: h = x @ emb_w.T + emb_b   (transpose weights to [f][c] first)
  transpose_w<<<(128 * 64 + 255) / 256, blk, 0, stream>>>(emb_w, embT, 128, 64);

  int gR = (N + 63) / 64;  // 782 row-blocks
  gemm_kernel<128, 1><<<dim3(gR, 1), blk, 0, stream>>>(x, embT, emb_b, nullptr, hA, nullptr, nullptr, N);

  // layer 0: F=64, H=2
  gemm_kernel<64, 2><<<dim3(gR, 2), blk, 0, stream>>>(hA, w0, nullptr, a0, xh, si, sj, N);
  agg_kernel<2><<<(N + 3) / 4, blk, 0, stream>>>(xh, si, sj, rp, col, hB, N);

  // layer 1: F=128, H=2
  gemm_kernel<128, 2><<<dim3(gR, 2), blk, 0, stream>>>(hB, w1, nullptr, a1, xh, si, sj, N);
  agg_kernel<2><<<(N + 3) / 4, blk, 0, stream>>>(xh, si, sj, rp, col, hA, N);

  // layer 2: F=128, H=1 -> output
  gemm_kernel<128, 1><<<dim3(gR, 1), blk, 0, stream>>>(hA, w2, nullptr, a2, xh, si, sj, N);
  agg_kernel<1><<<(N + 3) / 4, blk, 0, stream>>>(xh, si, sj, rp, col, (float*)d_out, N);
}

// Round 3
// 501.198 us; speedup vs baseline: 1.8502x; 1.2180x over previous
//
#include <hip/hip_runtime.h>
#include <math.h>

// ---------------- wave helpers ----------------
__device__ __forceinline__ float wred_sum(float v) {
#pragma unroll
  for (int o = 32; o; o >>= 1) v += __shfl_xor(v, o, 64);
  return v;
}
__device__ __forceinline__ float wred_max(float v) {
#pragma unroll
  for (int o = 32; o; o >>= 1) v = fmaxf(v, __shfl_xor(v, o, 64));
  return v;
}

// ---------------- CSR build ----------------
__global__ void zero_int(int* __restrict__ p, int n) {
  int i = blockIdx.x * blockDim.x + threadIdx.x;
  if (i < n) p[i] = 0;
}

// edges e in [0, E0) come from edge_index; e in [E0, E0+N) are self-loops (node e-E0)
__global__ void hist_kernel(const int* __restrict__ ei, int* __restrict__ cnt, int E0, int N) {
  int e = blockIdx.x * blockDim.x + threadIdx.x;
  if (e >= E0 + N) return;
  int d = (e < E0) ? ei[E0 + e] : (e - E0);
  atomicAdd(&cnt[d], 1);
}

__global__ void scan1(const int* __restrict__ cnt, int* __restrict__ part, int N) {
  __shared__ int lds[256];
  int idx = blockIdx.x * 256 + threadIdx.x;
  int v = (idx < N) ? cnt[idx] : 0;
  lds[threadIdx.x] = v;
  __syncthreads();
  for (int o = 128; o; o >>= 1) {
    if (threadIdx.x < o) lds[threadIdx.x] += lds[threadIdx.x + o];
    __syncthreads();
  }
  if (threadIdx.x == 0) part[blockIdx.x] = lds[0];
}

__global__ void scan2(int* __restrict__ part, int nb, int* __restrict__ rp, int N, int E) {
  __shared__ int lds[256];
  int t = threadIdx.x;
  int v = (t < nb) ? part[t] : 0;
  lds[t] = v;
  __syncthreads();
  for (int o = 1; o < 256; o <<= 1) {
    int x = (t >= o) ? lds[t - o] : 0;
    __syncthreads();
    lds[t] += x;
    __syncthreads();
  }
  part[t] = lds[t] - v;  // exclusive
  if (t == 0) rp[N] = E;
}

__global__ void scan3(const int* __restrict__ cnt, const int* __restrict__ part,
                      int* __restrict__ rp, int N) {
  __shared__ int lds[256];
  int t = threadIdx.x;
  int idx = blockIdx.x * 256 + t;
  int v = (idx < N) ? cnt[idx] : 0;
  lds[t] = v;
  __syncthreads();
  for (int o = 1; o < 256; o <<= 1) {
    int x = (t >= o) ? lds[t - o] : 0;
    __syncthreads();
    lds[t] += x;
    __syncthreads();
  }
  if (idx < N) rp[idx] = part[blockIdx.x] + lds[t] - v;
}

__global__ void fill_kernel(const int* __restrict__ ei, const int* __restrict__ rp,
                            int* __restrict__ cnt, int* __restrict__ col, int E0, int N) {
  int e = blockIdx.x * blockDim.x + threadIdx.x;
  if (e >= E0 + N) return;
  int d, s;
  if (e < E0) { s = ei[e]; d = ei[E0 + e]; }
  else        { s = e - E0; d = s; }
  int pos = rp[d] + atomicAdd(&cnt[d], 1);
  col[pos] = s;
}

// ---------------- emb_w transpose: (C=64, F=128) -> [f][c] ----------------
__global__ void transpose_w(const float* __restrict__ w, float* __restrict__ wt, int F, int C) {
  int i = blockIdx.x * blockDim.x + threadIdx.x;
  if (i < F * C) {
    int f = i / C, c = i % C;
    wt[i] = w[c * F + f];
  }
}

// ---------------- fused GEMM + attention scores, lane = row ----------------
// 64-thread blocks (1 wave). grid = (ceil(N/64), H). Each lane owns one output
// row: acc[64] in VGPRs. Weights are read with WAVE-UNIFORM addresses
// ([f][c] layout, f/c loop-uniform) -> scalar loads, off the VALU/VMEM pipes.
// x is staged per 64-f chunk into LDS (coalesced), read back per-lane with
// pad-65 -> bank = (lane+f)%32, 2-way aliasing (free).
// Scores si/sj are per-lane register dot products (no shuffles).
template <int F, int H, bool SCORES, bool BIAS>
__global__ __launch_bounds__(64) void gemm_rl(
    const float* __restrict__ in, const float* __restrict__ w,
    const float* __restrict__ bias, const float* __restrict__ a,
    float* __restrict__ xh, float* __restrict__ si, float* __restrict__ sj,
    int nrows) {
  constexpr int PAD = 65;
  __shared__ float xl[64 * PAD];
  const int lane = threadIdx.x;
  const int h = blockIdx.y;
  const int n0 = blockIdx.x * 64;
  int n = n0 + lane;
  if (n >= nrows) n = nrows - 1;  // tail lanes duplicate row N-1 (benign)

  const float* __restrict__ wq = w + (size_t)h * F * 64;

  float acc[64];
  if (BIAS) {
#pragma unroll
    for (int cq = 0; cq < 16; ++cq) {
      const float4 bv = reinterpret_cast<const float4*>(bias)[cq];  // uniform
      acc[cq * 4 + 0] = bv.x; acc[cq * 4 + 1] = bv.y;
      acc[cq * 4 + 2] = bv.z; acc[cq * 4 + 3] = bv.w;
    }
  } else {
#pragma unroll
    for (int c = 0; c < 64; ++c) acc[c] = 0.f;
  }

#pragma unroll
  for (int ch = 0; ch < F; ch += 64) {
    __syncthreads();
    // stage 64 rows x 64 f: 1024 float4 over 64 lanes = 16 iters
#pragma unroll
    for (int it = 0; it < 16; ++it) {
      const int idx = it * 64 + lane;   // float4 index in tile
      const int row = idx >> 4;         // 16 float4 per row
      const int cq = idx & 15;
      int rg = n0 + row;
      if (rg >= nrows) rg = nrows - 1;
      const float4 v = *reinterpret_cast<const float4*>(in + (size_t)rg * F + ch + cq * 4);
      float* d = xl + row * PAD + cq * 4;
      d[0] = v.x; d[1] = v.y; d[2] = v.z; d[3] = v.w;
    }
    __syncthreads();

    const float* xr = xl + lane * PAD;
#pragma unroll 4
    for (int f = 0; f < 64; ++f) {
      const float xv = xr[f];
      const float4* wrow = reinterpret_cast<const float4*>(wq + (size_t)(ch + f) * 64);
#pragma unroll
      for (int cq = 0; cq < 16; ++cq) {
        const float4 wv = wrow[cq];  // wave-uniform -> s_load
        acc[cq * 4 + 0] = fmaf(xv, wv.x, acc[cq * 4 + 0]);
        acc[cq * 4 + 1] = fmaf(xv, wv.y, acc[cq * 4 + 1]);
        acc[cq * 4 + 2] = fmaf(xv, wv.z, acc[cq * 4 + 2]);
        acc[cq * 4 + 3] = fmaf(xv, wv.w, acc[cq * 4 + 3]);
      }
    }
  }

  constexpr int HC = H * 64;
  float* orow = xh + (size_t)n * HC + h * 64;
#pragma unroll
  for (int cq = 0; cq < 16; ++cq) {
    float4 o;
    o.x = acc[cq * 4 + 0]; o.y = acc[cq * 4 + 1];
    o.z = acc[cq * 4 + 2]; o.w = acc[cq * 4 + 3];
    reinterpret_cast<float4*>(orow)[cq] = o;
  }

  if (SCORES) {
    float vi = 0.f, vj = 0.f;
#pragma unroll
    for (int cq = 0; cq < 16; ++cq) {
      const float4 av = reinterpret_cast<const float4*>(a + h * 128)[cq];       // uniform
      const float4 bv = reinterpret_cast<const float4*>(a + h * 128 + 64)[cq];  // uniform
      vi = fmaf(acc[cq * 4 + 0], av.x, vi); vj = fmaf(acc[cq * 4 + 0], bv.x, vj);
      vi = fmaf(acc[cq * 4 + 1], av.y, vi); vj = fmaf(acc[cq * 4 + 1], bv.y, vj);
      vi = fmaf(acc[cq * 4 + 2], av.z, vi); vj = fmaf(acc[cq * 4 + 2], bv.z, vj);
      vi = fmaf(acc[cq * 4 + 3], av.w, vi); vj = fmaf(acc[cq * 4 + 3], bv.w, vj);
    }
    si[(size_t)n * H + h] = vi;
    sj[(size_t)n * H + h] = vj;
  }
}

// ---------------- per-node online-softmax aggregation ----------------
// One wave per node. H==2: lane owns features (2*lane, 2*lane+1) of the 128-wide
// concat row. H==1: lane owns feature lane of 64.
template <int H>
__global__ __launch_bounds__(256) void agg_kernel(
    const float* __restrict__ xh, const float* __restrict__ si_g, const float* __restrict__ sj_g,
    const int* __restrict__ rp, const int* __restrict__ col,
    float* __restrict__ out, int N) {
  int lane = threadIdx.x & 63, wv = threadIdx.x >> 6;
  int n = blockIdx.x * 4 + wv;
  if (n >= N) return;
  int base = rp[n];
  int deg = rp[n + 1] - base;

  float si0 = si_g[n * H];
  float si1 = (H == 2) ? si_g[n * H + 1] : 0.f;
  float m0 = -INFINITY, m1 = -INFINITY;
  float d0 = 0.f, d1 = 0.f;
  float a0 = 0.f, a1 = 0.f;

  for (int start = 0; start < deg; start += 64) {
    int k = start + lane;
    bool vld = k < deg;
    int s = vld ? col[base + k] : 0;
    float al0 = -INFINITY, al1 = -INFINITY;
    if (vld) {
      if (H == 2) {
        float2 sjv = *reinterpret_cast<const float2*>(sj_g + (size_t)s * 2);
        float t0 = si0 + sjv.x; al0 = (t0 > 0.f) ? t0 : 0.2f * t0;
        float t1 = si1 + sjv.y; al1 = (t1 > 0.f) ? t1 : 0.2f * t1;
      } else {
        float t0 = si0 + sj_g[s]; al0 = (t0 > 0.f) ? t0 : 0.2f * t0;
      }
    }
    // chunk max + online rescale
    float nm0 = fmaxf(m0, wred_max(al0));
    float r0 = __expf(m0 - nm0);
    d0 *= r0; a0 *= r0; m0 = nm0;
    float p0 = vld ? __expf(al0 - m0) : 0.f;
    d0 += wred_sum(p0);
    float p1 = 0.f;
    if (H == 2) {
      float nm1 = fmaxf(m1, wred_max(al1));
      float r1 = __expf(m1 - nm1);
      d1 *= r1; a1 *= r1; m1 = nm1;
      p1 = vld ? __expf(al1 - m1) : 0.f;
      d1 += wred_sum(p1);
    }

    int cc = min(64, deg - start);
    if (H == 2) {
      for (int kk = 0; kk < cc; ++kk) {
        int ss = __shfl(s, kk, 64);
        float q0 = __shfl(p0, kk, 64);
        float q1 = __shfl(p1, kk, 64);
        float2 v = *reinterpret_cast<const float2*>(xh + (size_t)ss * 128 + lane * 2);
        float q = (lane < 32) ? q0 : q1;
        a0 = fmaf(q, v.x, a0);
        a1 = fmaf(q, v.y, a1);
      }
    } else {
      for (int kk = 0; kk < cc; ++kk) {
        int ss = __shfl(s, kk, 64);
        float q0 = __shfl(p0, kk, 64);
        a0 = fmaf(q0, xh[(size_t)ss * 64 + lane], a0);
      }
    }
  }

  if (H == 2) {
    float dd = (lane < 32) ? d0 : d1;
    float inv = 1.f / (dd + 1e-16f);
    float v0 = a0 * inv, v1 = a1 * inv;
    v0 = (v0 > 0.f) ? v0 : expm1f(v0);
    v1 = (v1 > 0.f) ? v1 : expm1f(v1);
    float2 o; o.x = v0; o.y = v1;
    *reinterpret_cast<float2*>(out + (size_t)n * 128 + lane * 2) = o;
  } else {
    float inv = 1.f / (d0 + 1e-16f);
    float v0 = a0 * inv;
    v0 = (v0 > 0.f) ? v0 : expm1f(v0);
    out[(size_t)n * 64 + lane] = v0;
  }
}

// ---------------- launch ----------------
extern "C" void kernel_launch(void* const* d_in, const int* in_sizes, int n_in,
                              void* d_out, int out_size, void* d_ws, size_t ws_size,
                              hipStream_t stream) {
  const float* x     = (const float*)d_in[0];
  const int*   ei    = (const int*)d_in[1];
  const float* emb_w = (const float*)d_in[2];
  const float* emb_b = (const float*)d_in[3];
  const float* w0    = (const float*)d_in[4];
  const float* a0    = (const float*)d_in[5];
  const float* w1    = (const float*)d_in[6];
  const float* a1    = (const float*)d_in[7];
  const float* w2    = (const float*)d_in[8];
  const float* a2    = (const float*)d_in[9];

  const int IN_CH = 128;
  int N  = in_sizes[0] / IN_CH;   // 50000
  int E0 = in_sizes[1] / 2;       // 800000
  int E  = E0 + N;                // with self-loops

  // workspace carve (256B aligned)
  char* p = (char*)d_ws;
  auto alloc = [&](size_t bytes) -> char* {
    char* r = p;
    p += (bytes + 255) & ~(size_t)255;
    return r;
  };
  float* hA   = (float*)alloc((size_t)N * 128 * 4);
  float* hB   = (float*)alloc((size_t)N * 128 * 4);
  float* xh   = (float*)alloc((size_t)N * 128 * 4);
  float* si   = (float*)alloc((size_t)N * 2 * 4);
  float* sj   = (float*)alloc((size_t)N * 2 * 4);
  float* embT = (float*)alloc(128 * 64 * 4);
  int* rp   = (int*)alloc((size_t)(N + 1) * 4);
  int* cnt  = (int*)alloc((size_t)N * 4);
  int* col  = (int*)alloc((size_t)E * 4);
  int* part = (int*)alloc(1024);

  dim3 blk(256);
  int gN = (N + 255) / 256;     // 196
  int gE = (E + 255) / 256;

  // CSR build
  zero_int<<<gN, blk, 0, stream>>>(cnt, N);
  hist_kernel<<<gE, blk, 0, stream>>>(ei, cnt, E0, N);
  scan1<<<gN, blk, 0, stream>>>(cnt, part, N);
  scan2<<<1, blk, 0, stream>>>(part, gN, rp, N, E);
  scan3<<<gN, blk, 0, stream>>>(cnt, part, rp, N);
  zero_int<<<gN, blk, 0, stream>>>(cnt, N);
  fill_kernel<<<gE, blk, 0, stream>>>(ei, rp, cnt, col, E0, N);

  // embedding: h = x @ emb_w.T + emb_b   (transpose weights to [f][c] first)
  transpose_w<<<(128 * 64 + 255) / 256, blk, 0, stream>>>(emb_w, embT, 128, 64);

  dim3 wblk(64);
  int gR = (N + 63) / 64;  // 782 row-blocks
  gemm_rl<128, 1, false, true><<<dim3(gR, 1), wblk, 0, stream>>>(x, embT, emb_b, nullptr, hA, nullptr, nullptr, N);

  // layer 0: F=64, H=2
  gemm_rl<64, 2, true, false><<<dim3(gR, 2), wblk, 0, stream>>>(hA, w0, nullptr, a0, xh, si, sj, N);
  agg_kernel<2><<<(N + 3) / 4, blk, 0, stream>>>(xh, si, sj, rp, col, hB, N);

  // layer 1: F=128, H=2
  gemm_rl<128, 2, true, false><<<dim3(gR, 2), wblk, 0, stream>>>(hB, w1, nullptr, a1, xh, si, sj, N);
  agg_kernel<2><<<(N + 3) / 4, blk, 0, stream>>>(xh, si, sj, rp, col, hA, N);

  // layer 2: F=128, H=1 -> output
  gemm_rl<128, 1, true, false><<<dim3(gR, 1), wblk, 0, stream>>>(hA, w2, nullptr, a2, xh, si, sj, N);
  agg_kernel<1><<<(N + 3) / 4, blk, 0, stream>>>(xh, si, sj, rp, col, (float*)d_out, N);
}

// Round 4
// 469.032 us; speedup vs baseline: 1.9771x; 1.0686x over previous
//
#include <hip/hip_runtime.h>
#include <math.h>

// ---------------- wave helpers ----------------
__device__ __forceinline__ float wred_sum(float v) {
#pragma unroll
  for (int o = 32; o; o >>= 1) v += __shfl_xor(v, o, 64);
  return v;
}
__device__ __forceinline__ float wred_max(float v) {
#pragma unroll
  for (int o = 32; o; o >>= 1) v = fmaxf(v, __shfl_xor(v, o, 64));
  return v;
}

// ---------------- CSR build ----------------
__global__ void zero_int(int* __restrict__ p, int n) {
  int i = blockIdx.x * blockDim.x + threadIdx.x;
  if (i < n) p[i] = 0;
}

// edges e in [0, E0) come from edge_index; e in [E0, E0+N) are self-loops (node e-E0)
__global__ void hist_kernel(const int* __restrict__ ei, int* __restrict__ cnt, int E0, int N) {
  int e = blockIdx.x * blockDim.x + threadIdx.x;
  if (e >= E0 + N) return;
  int d = (e < E0) ? ei[E0 + e] : (e - E0);
  atomicAdd(&cnt[d], 1);
}

__global__ void scan1(const int* __restrict__ cnt, int* __restrict__ part, int N) {
  __shared__ int lds[256];
  int idx = blockIdx.x * 256 + threadIdx.x;
  int v = (idx < N) ? cnt[idx] : 0;
  lds[threadIdx.x] = v;
  __syncthreads();
  for (int o = 128; o; o >>= 1) {
    if (threadIdx.x < o) lds[threadIdx.x] += lds[threadIdx.x + o];
    __syncthreads();
  }
  if (threadIdx.x == 0) part[blockIdx.x] = lds[0];
}

__global__ void scan2(int* __restrict__ part, int nb, int* __restrict__ rp, int N, int E) {
  __shared__ int lds[256];
  int t = threadIdx.x;
  int v = (t < nb) ? part[t] : 0;
  lds[t] = v;
  __syncthreads();
  for (int o = 1; o < 256; o <<= 1) {
    int x = (t >= o) ? lds[t - o] : 0;
    __syncthreads();
    lds[t] += x;
    __syncthreads();
  }
  part[t] = lds[t] - v;  // exclusive
  if (t == 0) rp[N] = E;
}

__global__ void scan3(const int* __restrict__ cnt, const int* __restrict__ part,
                      int* __restrict__ rp, int N) {
  __shared__ int lds[256];
  int t = threadIdx.x;
  int idx = blockIdx.x * 256 + t;
  int v = (idx < N) ? cnt[idx] : 0;
  lds[t] = v;
  __syncthreads();
  for (int o = 1; o < 256; o <<= 1) {
    int x = (t >= o) ? lds[t - o] : 0;
    __syncthreads();
    lds[t] += x;
    __syncthreads();
  }
  if (idx < N) rp[idx] = part[blockIdx.x] + lds[t] - v;
}

__global__ void fill_kernel(const int* __restrict__ ei, const int* __restrict__ rp,
                            int* __restrict__ cnt, int* __restrict__ col, int E0, int N) {
  int e = blockIdx.x * blockDim.x + threadIdx.x;
  if (e >= E0 + N) return;
  int d, s;
  if (e < E0) { s = ei[e]; d = ei[E0 + e]; }
  else        { s = e - E0; d = s; }
  int pos = rp[d] + atomicAdd(&cnt[d], 1);
  col[pos] = s;
}

// ---------------- emb_w transpose: (C=64, F=128) -> [f][c] ----------------
__global__ void transpose_w(const float* __restrict__ w, float* __restrict__ wt, int F, int C) {
  int i = blockIdx.x * blockDim.x + threadIdx.x;
  if (i < F * C) {
    int f = i / C, c = i % C;
    wt[i] = w[c * F + f];
  }
}

// ---------------- fused GEMM + attention scores, lane = row ----------------
// 64-thread blocks (1 wave). grid = (ceil(N/64), H). Each lane owns one output
// row: acc[64] in VGPRs. Weights are read with WAVE-UNIFORM addresses
// ([f][c] layout, f/c loop-uniform) -> scalar loads, off the VALU/VMEM pipes.
// x is staged per 64-f chunk into LDS (coalesced), read back per-lane with
// pad-65 -> bank = (lane+f)%32, 2-way aliasing (free).
// Scores si/sj are per-lane register dot products (no shuffles).
template <int F, int H, bool SCORES, bool BIAS>
__global__ __launch_bounds__(64) void gemm_rl(
    const float* __restrict__ in, const float* __restrict__ w,
    const float* __restrict__ bias, const float* __restrict__ a,
    float* __restrict__ xh, float* __restrict__ si, float* __restrict__ sj,
    int nrows) {
  constexpr int PAD = 65;
  __shared__ float xl[64 * PAD];
  const int lane = threadIdx.x;
  const int h = blockIdx.y;
  const int n0 = blockIdx.x * 64;
  int n = n0 + lane;
  if (n >= nrows) n = nrows - 1;  // tail lanes duplicate row N-1 (benign)

  const float* __restrict__ wq = w + (size_t)h * F * 64;

  float acc[64];
  if (BIAS) {
#pragma unroll
    for (int cq = 0; cq < 16; ++cq) {
      const float4 bv = reinterpret_cast<const float4*>(bias)[cq];  // uniform
      acc[cq * 4 + 0] = bv.x; acc[cq * 4 + 1] = bv.y;
      acc[cq * 4 + 2] = bv.z; acc[cq * 4 + 3] = bv.w;
    }
  } else {
#pragma unroll
    for (int c = 0; c < 64; ++c) acc[c] = 0.f;
  }

#pragma unroll
  for (int ch = 0; ch < F; ch += 64) {
    __syncthreads();
    // stage 64 rows x 64 f: 1024 float4 over 64 lanes = 16 iters
#pragma unroll
    for (int it = 0; it < 16; ++it) {
      const int idx = it * 64 + lane;   // float4 index in tile
      const int row = idx >> 4;         // 16 float4 per row
      const int cq = idx & 15;
      int rg = n0 + row;
      if (rg >= nrows) rg = nrows - 1;
      const float4 v = *reinterpret_cast<const float4*>(in + (size_t)rg * F + ch + cq * 4);
      float* d = xl + row * PAD + cq * 4;
      d[0] = v.x; d[1] = v.y; d[2] = v.z; d[3] = v.w;
    }
    __syncthreads();

    const float* xr = xl + lane * PAD;
#pragma unroll 4
    for (int f = 0; f < 64; ++f) {
      const float xv = xr[f];
      const float4* wrow = reinterpret_cast<const float4*>(wq + (size_t)(ch + f) * 64);
#pragma unroll
      for (int cq = 0; cq < 16; ++cq) {
        const float4 wv = wrow[cq];  // wave-uniform -> s_load
        acc[cq * 4 + 0] = fmaf(xv, wv.x, acc[cq * 4 + 0]);
        acc[cq * 4 + 1] = fmaf(xv, wv.y, acc[cq * 4 + 1]);
        acc[cq * 4 + 2] = fmaf(xv, wv.z, acc[cq * 4 + 2]);
        acc[cq * 4 + 3] = fmaf(xv, wv.w, acc[cq * 4 + 3]);
      }
    }
  }

  constexpr int HC = H * 64;
  float* orow = xh + (size_t)n * HC + h * 64;
#pragma unroll
  for (int cq = 0; cq < 16; ++cq) {
    float4 o;
    o.x = acc[cq * 4 + 0]; o.y = acc[cq * 4 + 1];
    o.z = acc[cq * 4 + 2]; o.w = acc[cq * 4 + 3];
    reinterpret_cast<float4*>(orow)[cq] = o;
  }

  if (SCORES) {
    float vi = 0.f, vj = 0.f;
#pragma unroll
    for (int cq = 0; cq < 16; ++cq) {
      const float4 av = reinterpret_cast<const float4*>(a + h * 128)[cq];       // uniform
      const float4 bv = reinterpret_cast<const float4*>(a + h * 128 + 64)[cq];  // uniform
      vi = fmaf(acc[cq * 4 + 0], av.x, vi); vj = fmaf(acc[cq * 4 + 0], bv.x, vj);
      vi = fmaf(acc[cq * 4 + 1], av.y, vi); vj = fmaf(acc[cq * 4 + 1], bv.y, vj);
      vi = fmaf(acc[cq * 4 + 2], av.z, vi); vj = fmaf(acc[cq * 4 + 2], bv.z, vj);
      vi = fmaf(acc[cq * 4 + 3], av.w, vi); vj = fmaf(acc[cq * 4 + 3], bv.w, vj);
    }
    si[(size_t)n * H + h] = vi;
    sj[(size_t)n * H + h] = vj;
  }
}

// ---------------- per-(node,head) online-softmax aggregation ----------------
// One wave per (node, head). lane = feature c (0..63): gathers are 256 B
// coalesced rows. wid = n*H + h so (n,0),(n,1) sit in the same block and share
// col/sj cache lines. Edge loop: softmax chunk phase is edge-parallel across
// lanes; accumulation phase is unrolled by 4 (4 independent row loads in
// flight). out[n][h*64+c] = ELU(acc/denom).
template <int H>
__global__ __launch_bounds__(256) void agg_kernel(
    const float* __restrict__ xh, const float* __restrict__ si_g, const float* __restrict__ sj_g,
    const int* __restrict__ rp, const int* __restrict__ col,
    float* __restrict__ out, int N) {
  constexpr int HC = H * 64;
  const int lane = threadIdx.x & 63;
  const int wid = blockIdx.x * 4 + (threadIdx.x >> 6);
  if (wid >= N * H) return;
  const int n = (H == 2) ? (wid >> 1) : wid;
  const int h = (H == 2) ? (wid & 1) : 0;

  const int base = rp[n];
  const int deg = rp[n + 1] - base;

  const float siv = si_g[(size_t)n * H + h];
  float m = -INFINITY, den = 0.f, acc = 0.f;

  for (int start = 0; start < deg; start += 64) {
    const int k = start + lane;
    const bool vld = k < deg;
    const int s = vld ? col[base + k] : 0;
    float al = -INFINITY;
    if (vld) {
      const float t = siv + sj_g[(size_t)s * H + h];
      al = (t > 0.f) ? t : 0.2f * t;
    }
    // chunk max + online rescale
    const float nm = fmaxf(m, wred_max(al));
    const float r = __expf(m - nm);
    den *= r; acc *= r; m = nm;
    const float p = vld ? __expf(al - m) : 0.f;
    den += wred_sum(p);

    const int cc = min(64, deg - start);
    int kk = 0;
    for (; kk + 4 <= cc; kk += 4) {
      const int s0 = __shfl(s, kk + 0, 64);
      const int s1 = __shfl(s, kk + 1, 64);
      const int s2 = __shfl(s, kk + 2, 64);
      const int s3 = __shfl(s, kk + 3, 64);
      const float q0 = __shfl(p, kk + 0, 64);
      const float q1 = __shfl(p, kk + 1, 64);
      const float q2 = __shfl(p, kk + 2, 64);
      const float q3 = __shfl(p, kk + 3, 64);
      const float v0 = xh[(size_t)s0 * HC + h * 64 + lane];
      const float v1 = xh[(size_t)s1 * HC + h * 64 + lane];
      const float v2 = xh[(size_t)s2 * HC + h * 64 + lane];
      const float v3 = xh[(size_t)s3 * HC + h * 64 + lane];
      acc = fmaf(q0, v0, acc);
      acc = fmaf(q1, v1, acc);
      acc = fmaf(q2, v2, acc);
      acc = fmaf(q3, v3, acc);
    }
    for (; kk < cc; ++kk) {
      const int ss = __shfl(s, kk, 64);
      const float qq = __shfl(p, kk, 64);
      acc = fmaf(qq, xh[(size_t)ss * HC + h * 64 + lane], acc);
    }
  }

  float v = acc / (den + 1e-16f);
  v = (v > 0.f) ? v : expm1f(v);
  out[(size_t)n * HC + h * 64 + lane] = v;
}

// ---------------- launch ----------------
extern "C" void kernel_launch(void* const* d_in, const int* in_sizes, int n_in,
                              void* d_out, int out_size, void* d_ws, size_t ws_size,
                              hipStream_t stream) {
  const float* x     = (const float*)d_in[0];
  const int*   ei    = (const int*)d_in[1];
  const float* emb_w = (const float*)d_in[2];
  const float* emb_b = (const float*)d_in[3];
  const float* w0    = (const float*)d_in[4];
  const float* a0    = (const float*)d_in[5];
  const float* w1    = (const float*)d_in[6];
  const float* a1    = (const float*)d_in[7];
  const float* w2    = (const float*)d_in[8];
  const float* a2    = (const float*)d_in[9];

  const int IN_CH = 128;
  int N  = in_sizes[0] / IN_CH;   // 50000
  int E0 = in_sizes[1] / 2;       // 800000
  int E  = E0 + N;                // with self-loops

  // workspace carve (256B aligned)
  char* p = (char*)d_ws;
  auto alloc = [&](size_t bytes) -> char* {
    char* r = p;
    p += (bytes + 255) & ~(size_t)255;
    return r;
  };
  float* hA   = (float*)alloc((size_t)N * 128 * 4);
  float* hB   = (float*)alloc((size_t)N * 128 * 4);
  float* xh   = (float*)alloc((size_t)N * 128 * 4);
  float* si   = (float*)alloc((size_t)N * 2 * 4);
  float* sj   = (float*)alloc((size_t)N * 2 * 4);
  float* embT = (float*)alloc(128 * 64 * 4);
  int* rp   = (int*)alloc((size_t)(N + 1) * 4);
  int* cnt  = (int*)alloc((size_t)N * 4);
  int* col  = (int*)alloc((size_t)E * 4);
  int* part = (int*)alloc(1024);

  dim3 blk(256);
  int gN = (N + 255) / 256;     // 196
  int gE = (E + 255) / 256;

  // CSR build
  zero_int<<<gN, blk, 0, stream>>>(cnt, N);
  hist_kernel<<<gE, blk, 0, stream>>>(ei, cnt, E0, N);
  scan1<<<gN, blk, 0, stream>>>(cnt, part, N);
  scan2<<<1, blk, 0, stream>>>(part, gN, rp, N, E);
  scan3<<<gN, blk, 0, stream>>>(cnt, part, rp, N);
  zero_int<<<gN, blk, 0, stream>>>(cnt, N);
  fill_kernel<<<gE, blk, 0, stream>>>(ei, rp, cnt, col, E0, N);

  // embedding: h = x @ emb_w.T + emb_b   (transpose weights to [f][c] first)
  transpose_w<<<(128 * 64 + 255) / 256, blk, 0, stream>>>(emb_w, embT, 128, 64);

  dim3 wblk(64);
  int gR = (N + 63) / 64;  // 782 row-blocks
  gemm_rl<128, 1, false, true><<<dim3(gR, 1), wblk, 0, stream>>>(x, embT, emb_b, nullptr, hA, nullptr, nullptr, N);

  // layer 0: F=64, H=2
  gemm_rl<64, 2, true, false><<<dim3(gR, 2), wblk, 0, stream>>>(hA, w0, nullptr, a0, xh, si, sj, N);
  agg_kernel<2><<<(N * 2 + 3) / 4, blk, 0, stream>>>(xh, si, sj, rp, col, hB, N);

  // layer 1: F=128, H=2
  gemm_rl<128, 2, true, false><<<dim3(gR, 2), wblk, 0, stream>>>(hB, w1, nullptr, a1, xh, si, sj, N);
  agg_kernel<2><<<(N * 2 + 3) / 4, blk, 0, stream>>>(xh, si, sj, rp, col, hA, N);

  // layer 2: F=128, H=1 -> output
  gemm_rl<128, 1, true, false><<<dim3(gR, 1), wblk, 0, stream>>>(hA, w2, nullptr, a2, xh, si, sj, N);
  agg_kernel<1><<<(N + 3) / 4, blk, 0, stream>>>(xh, si, sj, rp, col, (float*)d_out, N);
}